// Round 5
// baseline (792.497 us; speedup 1.0000x reference)
//
#include <hip/hip_runtime.h>
#include <cmath>

#define B64 64
#define H 1024
#define E 512
#define DG 64
#define GIN 2624   // E + 2H + DG
#define TZ 128
#define TU 256
#define V 8000
#define VT 8128    // V + TZ
#define NC 16128   // V + VT

using bf16x8 = __attribute__((ext_vector_type(8))) short;
using f32x4  = __attribute__((ext_vector_type(4))) float;

// pack two fp32 -> two bf16 in one dword
__device__ inline unsigned pack2(float a, float b) {
    unsigned ua = __float_as_uint(a) + 0x8000u;
    unsigned ub = __float_as_uint(b) + 0x8000u;
    return __builtin_amdgcn_perm(ub, ua, 0x07060302u);  // lo16=hi(a), hi16=hi(b)
}
__device__ inline uint2 pack4(float4 v) {
    return make_uint2(pack2(v.x, v.y), pack2(v.z, v.w));
}

// fast tanh via hw exp: tanh(x) = 1 - 2/(e^{2x}+1); exact at +-inf
__device__ inline float fast_tanh(float x) {
    float e = __expf(2.f * x);
    return 1.f - 2.f / (e + 1.f);
}
__device__ inline float fast_sig(float x) {
    return 1.f / (1.f + __expf(-x));
}

// async global->LDS, 16B per lane; lptr must be wave-uniform (HW adds lane*16)
__device__ inline void gl_lds16(const void* gptr, void* lptr) {
    __builtin_amdgcn_global_load_lds(
        (const __attribute__((address_space(1))) void*)gptr,
        (__attribute__((address_space(3))) void*)lptr, 16, 0, 0);
}

// ---------------------------------------------------------------------------
// Shared 64xN GEMM body: C(64,N) (+)= A(64, K-chunk) @ W(N,ldw)^T, bf16 MFMA.
// store=true: single-owner full-K block, plain store (no pre-zero needed).
// ---------------------------------------------------------------------------
__device__ __forceinline__ void gemm_core(
    short (*As)[40], short (*Bs)[40], int tid,
    const float* __restrict__ A, int lda,
    const float* __restrict__ W, int ldw, int koff,
    const float* __restrict__ bias,
    float* __restrict__ C, int N,
    int n0, int kb, int ke, bool addbias, bool store)
{
    const int wave = tid >> 6, lane = tid & 63;
    const int wm = wave >> 1, wn = wave & 1;
    const int q = lane >> 4, l16 = lane & 15;

    f32x4 acc[2][2];
#pragma unroll
    for (int i = 0; i < 2; ++i)
#pragma unroll
        for (int j = 0; j < 2; ++j) acc[i][j] = f32x4{0.f, 0.f, 0.f, 0.f};

    for (int ks = kb; ks < ke; ++ks) {
        const int k0 = ks * 32;
        __syncthreads();
#pragma unroll
        for (int i = 0; i < 2; ++i) {
            int slot = i * 256 + tid;
            int row  = slot >> 3;
            int kq   = (slot & 7) << 2;
            float4 a = *(const float4*)(A + (size_t)row * lda + k0 + kq);
            *(uint2*)&As[row][kq] = pack4(a);
            float4 w = *(const float4*)(W + (size_t)(n0 + row) * ldw + koff + k0 + kq);
            *(uint2*)&Bs[row][kq] = pack4(w);
        }
        __syncthreads();
        bf16x8 af[2], bfr[2];
#pragma unroll
        for (int t = 0; t < 2; ++t) af[t]  = *(bf16x8*)&As[wm * 32 + t * 16 + l16][q * 8];
#pragma unroll
        for (int t = 0; t < 2; ++t) bfr[t] = *(bf16x8*)&Bs[wn * 32 + t * 16 + l16][q * 8];
#pragma unroll
        for (int tm = 0; tm < 2; ++tm)
#pragma unroll
            for (int tn = 0; tn < 2; ++tn)
                acc[tm][tn] = __builtin_amdgcn_mfma_f32_16x16x32_bf16(
                    af[tm], bfr[tn], acc[tm][tn], 0, 0, 0);
    }

#pragma unroll
    for (int tm = 0; tm < 2; ++tm) {
#pragma unroll
        for (int r = 0; r < 4; ++r) {
            int b = wm * 32 + tm * 16 + q * 4 + r;
#pragma unroll
            for (int tn = 0; tn < 2; ++tn) {
                int n = n0 + wn * 32 + tn * 16 + l16;
                float v = acc[tm][tn][r];
                if (addbias) v += bias[n];
                if (store) C[(size_t)b * N + n] = v;
                else       atomicAdd(&C[(size_t)b * N + n], v);
            }
        }
    }
}

// ---------------------------------------------------------------------------
// Prep kernel. grid 28516, block 256. Linear block ranges:
//  [0,80)        : full-K store-mode GEMMs: hbz(16) | hbu(16) | gh(48)
//  [80,804)      : zero atomic accumulators: scores(32) | gi(192) | gen(500)
//  [804,28452)   : fp32->bf16 convert u_enc | z_enc | azW[:,1024:] | auW[:,1024:] | c2W
//  [28452,28516) : gather x[b] = [emb | . | . | degree]
// ---------------------------------------------------------------------------
__global__ __launch_bounds__(256) void k_prep(
    const float* __restrict__ u_enc, const float* __restrict__ z_enc,
    const float* __restrict__ azW, const float* __restrict__ auW,
    const float* __restrict__ c2W,
    unsigned short* __restrict__ ubf, unsigned short* __restrict__ zbf,
    unsigned short* __restrict__ azWbf, unsigned short* __restrict__ auWbf,
    unsigned short* __restrict__ c2Wbf,
    const int* __restrict__ mt, const float* __restrict__ embW,
    const float* __restrict__ degree, float* __restrict__ x,
    const float* __restrict__ h0,
    const float* __restrict__ azb, float* __restrict__ hbz,
    const float* __restrict__ aub, float* __restrict__ hbu,
    const float* __restrict__ Whh, const float* __restrict__ bhh,
    float* __restrict__ gh, float* __restrict__ ws)
{
    __shared__ short As[64][40];
    __shared__ short Bs[64][40];
    int n = blockIdx.x, tid = threadIdx.x;
    if (n < 80) {
        const float *W, *bias; float* C; int ldw, N, n0;
        if (n < 16)      { W = azW; bias = azb; C = hbz; ldw = 2048; N = 1024; n0 = n * 64; }
        else if (n < 32) { W = auW; bias = aub; C = hbu; ldw = 2048; N = 1024; n0 = (n - 16) * 64; }
        else             { W = Whh; bias = bhh; C = gh;  ldw = 1024; N = 3072; n0 = (n - 32) * 64; }
        gemm_core(As, Bs, tid, h0, 1024, W, ldw, 0, bias, C, N, n0, 0, 32, true, true);
        return;
    }
    if (n < 804) {      // zero blocks: 1024 floats each
        int zi = n - 80;
        size_t off;
        if (zi < 32)       off = (size_t)zi * 1024;                   // scores_z|scores_u
        else if (zi < 224) off = 163840 + (size_t)(zi - 32) * 1024;   // gi
        else               off = 557056 + (size_t)(zi - 224) * 1024;  // gen
        *(f32x4*)(ws + off + tid * 4) = f32x4{0.f, 0.f, 0.f, 0.f};
        return;
    }
    n -= 804;
    if (n >= 27648) {   // gather path
        int b = n - 27648;
        int m = mt[b];
        for (int k = tid; k < E; k += 256) x[(size_t)b * GIN + k] = embW[(size_t)m * E + k];
        if (tid < DG) x[(size_t)b * GIN + E + 2 * H + tid] = degree[b * DG + tid];
        return;
    }
    int k4 = tid * 4;
    const float* src; unsigned short* dst; int ld, koff, r;
    if (n < 16384)      { src = u_enc; dst = ubf;   ld = 1024; koff = 0;    r = n; }
    else if (n < 24576) { src = z_enc; dst = zbf;   ld = 1024; koff = 0;    r = n - 16384; }
    else if (n < 25600) { src = azW;   dst = azWbf; ld = 2048; koff = 1024; r = n - 24576; }
    else if (n < 26624) { src = auW;   dst = auWbf; ld = 2048; koff = 1024; r = n - 25600; }
    else                { src = c2W;   dst = c2Wbf; ld = 1024; koff = 0;    r = n - 26624; }
    float4 v = *(const float4*)(src + (size_t)r * ld + koff + k4);
    *(uint2*)(dst + (size_t)r * 1024 + k4) = pack4(v);
}

// ---------------------------------------------------------------------------
// Merged big fused kernel. grid 2048 linear, block 256.
//  gid < 1024 : z-side (M=8192, A=zbf). by = gid>>6:
//      by < 8 : scores_z epilogue (add=hbz, vec=azv)
//      by >= 8: tz = tanh(z @ c2W^T + c2b) materialized fp32
//  gid >= 1024: u-side (M=16384, A=ubf). scores_u epilogue (add=hbu, vec=auv)
// ---------------------------------------------------------------------------
__global__ __launch_bounds__(256) void ftd_all(
    const unsigned short* __restrict__ zbf_, const unsigned short* __restrict__ ubf_,
    const unsigned short* __restrict__ azWbf, const unsigned short* __restrict__ auWbf,
    const unsigned short* __restrict__ c2Wbf,
    const float* __restrict__ hbz, const float* __restrict__ hbu,
    const float* __restrict__ azv, const float* __restrict__ auv,
    const float* __restrict__ c2b,
    float* __restrict__ scores_z, float* __restrict__ scores_u,
    float* __restrict__ tz)
{
    __shared__ unsigned short As[128 * 32];
    __shared__ unsigned short Bs[128 * 32];
    const int tid  = threadIdx.x;
    const int wave = tid >> 6, lane = tid & 63;
    const int wm = wave >> 1, wn = wave & 1;
    const int q = lane >> 4, l16 = lane & 15;
    const int lrow = lane >> 2;
    const int lk   = (lane & 3) * 8;

    const int gid = blockIdx.x;
    const bool isU = gid >= 1024;
    int m0, n0;
    const unsigned short *A, *W;
    bool isTZ = false;
    const float* addv; const float* vvec; float* outs;
    if (isU) {
        int g = gid - 1024;
        m0 = (g & 127) * 128;
        n0 = (g >> 7) * 128;
        A = ubf_; W = auWbf;
        addv = hbu; vvec = auv; outs = scores_u;
    } else {
        m0 = (gid & 63) * 128;
        int by = gid >> 6;
        A = zbf_;
        if (by < 8) { n0 = by * 128; W = azWbf; addv = hbz; vvec = azv; outs = scores_z; }
        else        { n0 = (by - 8) * 128; W = c2Wbf; isTZ = true; addv = nullptr; vvec = nullptr; outs = nullptr; }
    }

    f32x4 acc[4][4];
#pragma unroll
    for (int i = 0; i < 4; ++i)
#pragma unroll
        for (int j = 0; j < 4; ++j) acc[i][j] = f32x4{0.f, 0.f, 0.f, 0.f};

    for (int kt = 0; kt < 32; ++kt) {
        const int k0 = kt * 32;
        __syncthreads();
#pragma unroll
        for (int j = 0; j < 2; ++j) {
            int r0 = (wave * 2 + j) * 16;
            gl_lds16(A + (size_t)(m0 + r0 + lrow) * 1024 + k0 + lk, &As[r0 * 32]);
            gl_lds16(W + (size_t)(n0 + r0 + lrow) * 1024 + k0 + lk, &Bs[r0 * 32]);
        }
        __syncthreads();
        bf16x8 af[4], bfr[4];
#pragma unroll
        for (int t = 0; t < 4; ++t) af[t]  = *(bf16x8*)&As[(wm * 64 + t * 16 + l16) * 32 + q * 8];
#pragma unroll
        for (int t = 0; t < 4; ++t) bfr[t] = *(bf16x8*)&Bs[(wn * 64 + t * 16 + l16) * 32 + q * 8];
#pragma unroll
        for (int tm = 0; tm < 4; ++tm)
#pragma unroll
            for (int tn = 0; tn < 4; ++tn)
                acc[tm][tn] = __builtin_amdgcn_mfma_f32_16x16x32_bf16(
                    af[tm], bfr[tn], acc[tm][tn], 0, 0, 0);
    }

    if (!isTZ) {
#pragma unroll
        for (int tm = 0; tm < 4; ++tm) {
#pragma unroll
            for (int r = 0; r < 4; ++r) {
                int R = m0 + wm * 64 + tm * 16 + q * 4 + r;
                int b = R & 63;
                float s = 0.f;
#pragma unroll
                for (int tn = 0; tn < 4; ++tn) {
                    int col = n0 + wn * 64 + tn * 16 + l16;
                    float e = acc[tm][tn][r] + addv[(size_t)b * 1024 + col];
                    s += fast_tanh(e) * vvec[col];
                }
                s += __shfl_xor(s, 1);
                s += __shfl_xor(s, 2);
                s += __shfl_xor(s, 4);
                s += __shfl_xor(s, 8);
                if (l16 == 0) atomicAdd(&outs[R], s);
            }
        }
    } else {
#pragma unroll
        for (int tm = 0; tm < 4; ++tm) {
#pragma unroll
            for (int r = 0; r < 4; ++r) {
                int R = m0 + wm * 64 + tm * 16 + q * 4 + r;
#pragma unroll
                for (int tn = 0; tn < 4; ++tn) {
                    int col = n0 + wn * 64 + tn * 16 + l16;
                    tz[(size_t)R * 1024 + col] = fast_tanh(acc[tm][tn][r] + c2b[col]);
                }
            }
        }
    }
}

// softmax over t + ctx, both sides in one launch. grid (64,4), block 256.
//  y<2: z side (T=128), y>=2: u side (T=256); hc = y&1 selects h-half.
__global__ __launch_bounds__(256) void k_softmax_ctx_bf(
    const float* __restrict__ scores_z, const float* __restrict__ scores_u,
    const unsigned short* __restrict__ zbf_, const unsigned short* __restrict__ ubf_,
    float* __restrict__ x, float* __restrict__ y)
{
    __shared__ float red[256];
    __shared__ float al[256];
    int b = blockIdx.x, tid = threadIdx.x;
    int side = blockIdx.y >> 1, hc = blockIdx.y & 1;
    const float* scores = side ? scores_u : scores_z;
    const unsigned short* encbf = side ? ubf_ : zbf_;
    int T = side ? TU : TZ;
    int xoff = side ? 512 : 1536;
    int yoff = side ? 1024 : 0;

    float s = (tid < T) ? scores[tid * B64 + b] : -1e30f;
    red[tid] = s; __syncthreads();
    for (int off = 128; off > 0; off >>= 1) {
        if (tid < off) red[tid] = fmaxf(red[tid], red[tid + off]);
        __syncthreads();
    }
    float mx = red[0]; __syncthreads();
    float e = (tid < T) ? __expf(s - mx) : 0.f;
    red[tid] = e; __syncthreads();
    for (int off = 128; off > 0; off >>= 1) {
        if (tid < off) red[tid] += red[tid + off];
        __syncthreads();
    }
    float inv = 1.f / red[0];
    al[tid] = e * inv;
    __syncthreads();
    int h = hc * 512 + tid * 2;
    float a0 = 0.f, a1 = 0.f;
#pragma unroll 4
    for (int t = 0; t < T; ++t) {
        unsigned u = *(const unsigned*)(encbf + ((size_t)t * B64 + b) * 1024 + h);
        float w = al[t];
        a0 += w * __uint_as_float(u << 16);
        a1 += w * __uint_as_float(u & 0xffff0000u);
    }
    x[(size_t)b * GIN + xoff + h]     = a0;
    x[(size_t)b * GIN + xoff + h + 1] = a1;
    y[(size_t)b * 3072 + yoff + h]     = a0;
    y[(size_t)b * 3072 + yoff + h + 1] = a1;
}

// ---------------------------------------------------------------------------
// gi GEMM + genA (gen K=0..2047, needs only y[:,0:2048]). grid 884.
//  n < 500 : genA  (n0=(g%125)*64, kc=g/125 of 4, K-steps kc*16..+16)
//  n >= 500: gi = x @ Wih^T + bih (n0, kc of 8, 11 k-steps each)
// ---------------------------------------------------------------------------
__global__ __launch_bounds__(256) void k_gi_genA(
    const float* __restrict__ x, const float* __restrict__ Wih,
    const float* __restrict__ bih, float* __restrict__ gi,
    const float* __restrict__ y, const float* __restrict__ pW,
    float* __restrict__ gen)
{
    __shared__ short As[64][40];
    __shared__ short Bs[64][40];
    int n = blockIdx.x, tid = threadIdx.x;
    if (n < 500) {
        int n0 = (n % 125) * 64;
        int kc = n / 125;
        gemm_core(As, Bs, tid, y, 3072, pW, 3072, 0, nullptr, gen, 8000,
                  n0, kc * 16, kc * 16 + 16, false, false);
    } else {
        int g = n - 500;
        int n0 = (g % 48) * 64;
        int kc = g / 48;
        int kb = kc * 11, ke = min(kb + 11, 82);
        gemm_core(As, Bs, tid, x, GIN, Wih, GIN, 0, bih, gi, 3072,
                  n0, kb, ke, kc == 0, false);
    }
}

// ---------------------------------------------------------------------------
// GRU gate (recomputed per block, LDS-resident) + z_cs dot.
// grid (64,4), block 512. quarter-0 blocks write gru outputs.
// zraw[b*TZ + t] = dot(tanh-energy tz[t*64+b,:], gate(b,:)).
// ---------------------------------------------------------------------------
__global__ __launch_bounds__(512) void k_zcs_gate(
    const float* __restrict__ gi, const float* __restrict__ gh,
    const float* __restrict__ h0, const float* __restrict__ tz,
    float* __restrict__ zraw,
    float* __restrict__ y, float* __restrict__ out_hid,
    float* __restrict__ out_gru)
{
    __shared__ float g[1024];
    int b = blockIdx.x, quarter = blockIdx.y, tid = threadIdx.x;
    int wave = tid >> 6, lane = tid & 63;
    for (int j = tid; j < H; j += 512) {
        float ir = gi[(size_t)b * 3072 + j];
        float iz = gi[(size_t)b * 3072 + H + j];
        float in_ = gi[(size_t)b * 3072 + 2 * H + j];
        float hr = gh[(size_t)b * 3072 + j];
        float hz = gh[(size_t)b * 3072 + H + j];
        float hn = gh[(size_t)b * 3072 + 2 * H + j];
        float r = fast_sig(ir + hr);
        float z = fast_sig(iz + hz);
        float nn = fast_tanh(in_ + r * hn);
        float h = h0[(size_t)b * H + j];
        float o = (1.f - z) * nn + z * h;
        g[j] = o;
        if (quarter == 0) {
            y[(size_t)b * 3072 + 2 * H + j] = o;
            out_hid[(size_t)b * H + j] = o;
            out_gru[(size_t)b * H + j] = o;
        }
    }
    __syncthreads();
    float gr[16];
#pragma unroll
    for (int j = 0; j < 16; ++j) gr[j] = g[lane * 16 + j];
    int t0 = quarter * 32;
#pragma unroll
    for (int i = 0; i < 4; ++i) {
        int t = t0 + wave + i * 8;
        const float* row = tz + ((size_t)t * B64 + b) * 1024 + lane * 16;
        float s = 0.f;
#pragma unroll
        for (int c = 0; c < 4; ++c) {
            float4 v = *(const float4*)(row + c * 4);
            s += v.x * gr[c * 4 + 0] + v.y * gr[c * 4 + 1]
               + v.z * gr[c * 4 + 2] + v.w * gr[c * 4 + 3];
        }
#pragma unroll
        for (int off = 32; off > 0; off >>= 1) s += __shfl_xor(s, off);
        if (lane == 0) zraw[b * TZ + t] = s;
    }
}

// ---------------------------------------------------------------------------
// Merged genB GEMM + sparse log-sum-exp. grid 762, block 256.
//  n < 512  : sparse (c = n&7, b = n>>3)  -- BW-bound, dispatched first
//  n >= 512 : genB (gen K=2048..3071, bias carried by kc==0)
// ---------------------------------------------------------------------------
__global__ __launch_bounds__(256) void k_gen_sparse(
    const float* __restrict__ y, const float* __restrict__ pW,
    const float* __restrict__ pb, float* __restrict__ gen,
    const float* __restrict__ sz, const float* __restrict__ zraw,
    float* __restrict__ zcopy)
{
    __shared__ short As[64][40];
    __shared__ short Bs[64][40];
    __shared__ float es[TZ];
    __shared__ float mred[2];
    int n = blockIdx.x, tid = threadIdx.x;
    if (n >= 512) {
        int g = n - 512;
        int n0 = (g % 125) * 64;
        int kc = g / 125;             // 0 or 1
        int kb = 64 + kc * 16;
        gemm_core(As, Bs, tid, y, 3072, pW, 3072, 0, pb, gen, 8000,
                  n0, kb, kb + 16, kc == 0, false);
        return;
    }
    int c = n & 7, b = n >> 3;
    float sv = 0.f;
    if (tid < TZ) {
        sv = zraw[b * TZ + tid];
        float mm = sv;
#pragma unroll
        for (int off = 32; off > 0; off >>= 1) mm = fmaxf(mm, __shfl_xor(mm, off));
        if ((tid & 63) == 0) mred[tid >> 6] = mm;
    }
    __syncthreads();
    float m = fmaxf(mred[0], mred[1]);
    if (tid < TZ) es[tid] = __expf(sv - m);
    __syncthreads();
    if (tid >= 254) return;
    int v4 = c * 254 + tid;               // 8 * 254 = 2032 = 8128/4, exact cover
    const f32x4* base = (const f32x4*)(sz + (size_t)b * TZ * VT);
    float4 acc = make_float4(0.f, 0.f, 0.f, 0.f);
#pragma unroll 16
    for (int t = 0; t < TZ; ++t) {
        f32x4 xv = __builtin_nontemporal_load(&base[(size_t)t * (VT / 4) + v4]);
        float e = es[t];
        acc.x += e * xv[0]; acc.y += e * xv[1]; acc.z += e * xv[2]; acc.w += e * xv[3];
    }
    int v = v4 * 4;
    zcopy[(size_t)b * VT + v + 0] = __logf(acc.x) + m;
    zcopy[(size_t)b * VT + v + 1] = __logf(acc.y) + m;
    zcopy[(size_t)b * VT + v + 2] = __logf(acc.z) + m;
    zcopy[(size_t)b * VT + v + 3] = __logf(acc.w) + m;
}

// final softmax over [gen(8000) | zcopy(8128)]; proba combine. grid 64, block 1024.
__global__ __launch_bounds__(1024) void k_final(
    const float* __restrict__ gen, const float* __restrict__ zcopy,
    float* __restrict__ proba)
{
    __shared__ float lg[NC];
    __shared__ float wred[16];
    int b = blockIdx.x, tid = threadIdx.x;
    int lane = tid & 63, wave = tid >> 6;
    for (int i = tid; i < V; i += 1024) lg[i] = gen[(size_t)b * V + i];
    for (int i = tid; i < VT; i += 1024) lg[V + i] = zcopy[(size_t)b * VT + i];
    __syncthreads();
    float mx = -1e30f;
    for (int i = tid; i < NC; i += 1024) mx = fmaxf(mx, lg[i]);
#pragma unroll
    for (int off = 32; off > 0; off >>= 1) mx = fmaxf(mx, __shfl_xor(mx, off));
    if (lane == 0) wred[wave] = mx;
    __syncthreads();
    mx = wred[0];
#pragma unroll
    for (int w = 1; w < 16; ++w) mx = fmaxf(mx, wred[w]);
    __syncthreads();
    float sm = 0.f;
    for (int i = tid; i < NC; i += 1024) sm += __expf(lg[i] - mx);
#pragma unroll
    for (int off = 32; off > 0; off >>= 1) sm += __shfl_xor(sm, off);
    if (lane == 0) wred[wave] = sm;
    __syncthreads();
    float Z = 0.f;
#pragma unroll
    for (int w = 0; w < 16; ++w) Z += wred[w];
    float invZ = 1.f / Z;
    for (int v = tid; v < VT; v += 1024) {
        float p = __expf(lg[V + v] - mx) * invZ;
        if (v < V) p += __expf(lg[v] - mx) * invZ;
        proba[(size_t)b * VT + v] = p;
    }
}

extern "C" void kernel_launch(void* const* d_in, const int* in_sizes, int n_in,
                              void* d_out, int out_size, void* d_ws, size_t ws_size,
                              hipStream_t stream)
{
    const float* z_enc  = (const float*)d_in[0];
    const float* u_enc  = (const float*)d_in[1];
    const int*   mt     = (const int*)d_in[2];
    const float* degree = (const float*)d_in[3];
    const float* h0     = (const float*)d_in[4];
    const float* sz     = (const float*)d_in[5];
    const float* embW   = (const float*)d_in[6];
    const float* azW    = (const float*)d_in[7];
    const float* azb    = (const float*)d_in[8];
    const float* azv    = (const float*)d_in[9];
    const float* auW    = (const float*)d_in[10];
    const float* aub    = (const float*)d_in[11];
    const float* auv    = (const float*)d_in[12];
    const float* Wih    = (const float*)d_in[13];
    const float* Whh    = (const float*)d_in[14];
    const float* bih    = (const float*)d_in[15];
    const float* bhh    = (const float*)d_in[16];
    const float* pW     = (const float*)d_in[17];
    const float* pb     = (const float*)d_in[18];
    const float* c2W    = (const float*)d_in[19];
    const float* c2b    = (const float*)d_in[20];

    float* ws       = (float*)d_ws;
    // atomic accumulators (zeroed by k_prep zero-blocks):
    float* scores_z = ws;               // 8192   (t*64+b)
    float* scores_u = ws + 8192;        // 16384
    float* hbz      = ws + 32768;       // 65536  (store-mode, no zero)
    float* hbu      = ws + 98304;       // 65536  (store-mode, no zero)
    float* gi       = ws + 163840;      // 196608 (64*3072)
    float* gh       = ws + 360448;      // 196608 (store-mode, no zero)
    float* gen      = ws + 557056;      // 512000 (64*8000)
    // non-zeroed:
    float* x        = ws + 1069056;     // 64*2624
    float* y        = ws + 1236992;     // 64*3072
    float* zcopy    = ws + 1507392;     // 64*8128
    float* tz       = ws + 2027584;     // 8192*1024 fp32 tanh-energy
    // bf16 area (shorts)
    unsigned short* ubf   = (unsigned short*)(ws + 2027584 + 8388608);
    unsigned short* zbf   = ubf + (size_t)16384 * 1024;
    unsigned short* azWbf = zbf + (size_t)8192 * 1024;
    unsigned short* auWbf = azWbf + (size_t)1024 * 1024;
    unsigned short* c2Wbf = auWbf + (size_t)1024 * 1024;
    // scratch after bf16 area (float offset 24,571,968)
    float* zraw = ws + 24571968;        // 64*128

    float* out_proba = (float*)d_out;
    float* out_hid   = out_proba + (size_t)B64 * VT;
    float* out_gru   = out_hid + (size_t)B64 * H;

    // prep: store-mode small GEMMs + zero-fill + fp32->bf16 convert + x gather
    k_prep<<<28516, 256, 0, stream>>>(u_enc, z_enc, azW, auW, c2W,
                                      ubf, zbf, azWbf, auWbf, c2Wbf,
                                      mt, embW, degree, x,
                                      h0, azb, hbz, aub, hbu, Whh, bhh, gh, ws);

    // merged big fused kernel: scores_z + tz + scores_u
    ftd_all<<<2048, 256, 0, stream>>>(zbf, ubf, azWbf, auWbf, c2Wbf,
                                      hbz, hbu, azv, auv, c2b,
                                      scores_z, scores_u, tz);

    // softmax over t + ctx, both sides
    k_softmax_ctx_bf<<<dim3(64, 4), 256, 0, stream>>>(scores_z, scores_u, zbf, ubf, x, y);

    // gi GEMM + genA (K 0..2047 of gen, overlapped BW)
    k_gi_genA<<<884, 256, 0, stream>>>(x, Wih, bih, gi, y, pW, gen);

    // GRU gate (LDS-recompute) + z_cs dot
    k_zcs_gate<<<dim3(64, 4), 512, 0, stream>>>(gi, gh, h0, tz, zraw, y, out_hid, out_gru);

    // genB (K 2048..3071 + bias) + sparse log-sum-exp, one launch
    k_gen_sparse<<<762, 256, 0, stream>>>(y, pW, pb, gen, sz, zraw, zcopy);

    // final softmax + combine
    k_final<<<64, 1024, 0, stream>>>(gen, zcopy, out_proba);
}

// Round 6
// 728.668 us; speedup vs baseline: 1.0876x; 1.0876x over previous
//
#include <hip/hip_runtime.h>
#include <cmath>

#define B64 64
#define H 1024
#define E 512
#define DG 64
#define GIN 2624   // E + 2H + DG
#define TZ 128
#define TU 256
#define V 8000
#define VT 8128    // V + TZ
#define NC 16128   // V + VT

using bf16x8 = __attribute__((ext_vector_type(8))) short;
using f32x4  = __attribute__((ext_vector_type(4))) float;

// pack two fp32 -> two bf16 in one dword
__device__ inline unsigned pack2(float a, float b) {
    unsigned ua = __float_as_uint(a) + 0x8000u;
    unsigned ub = __float_as_uint(b) + 0x8000u;
    return __builtin_amdgcn_perm(ub, ua, 0x07060302u);  // lo16=hi(a), hi16=hi(b)
}
__device__ inline uint2 pack4(float4 v) {
    return make_uint2(pack2(v.x, v.y), pack2(v.z, v.w));
}

// fast tanh via hw exp: tanh(x) = 1 - 2/(e^{2x}+1); exact at +-inf
__device__ inline float fast_tanh(float x) {
    float e = __expf(2.f * x);
    return 1.f - 2.f / (e + 1.f);
}
__device__ inline float fast_sig(float x) {
    return 1.f / (1.f + __expf(-x));
}

// async global->LDS, 16B per lane; lptr must be wave-uniform (HW adds lane*16)
__device__ inline void gl_lds16(const void* gptr, void* lptr) {
    __builtin_amdgcn_global_load_lds(
        (const __attribute__((address_space(1))) void*)gptr,
        (__attribute__((address_space(3))) void*)lptr, 16, 0, 0);
}

// ---------------------------------------------------------------------------
// Shared 64xN GEMM body: C(64,N) += A(64, K-chunk) @ W(N,ldw)^T, bf16 MFMA.
// ---------------------------------------------------------------------------
__device__ __forceinline__ void gemm_core(
    short (*As)[40], short (*Bs)[40], int tid,
    const float* __restrict__ A, int lda,
    const float* __restrict__ W, int ldw, int koff,
    const float* __restrict__ bias,
    float* __restrict__ C, int N,
    int n0, int kb, int ke, bool addbias)
{
    const int wave = tid >> 6, lane = tid & 63;
    const int wm = wave >> 1, wn = wave & 1;
    const int q = lane >> 4, l16 = lane & 15;

    f32x4 acc[2][2];
#pragma unroll
    for (int i = 0; i < 2; ++i)
#pragma unroll
        for (int j = 0; j < 2; ++j) acc[i][j] = f32x4{0.f, 0.f, 0.f, 0.f};

    for (int ks = kb; ks < ke; ++ks) {
        const int k0 = ks * 32;
        __syncthreads();
#pragma unroll
        for (int i = 0; i < 2; ++i) {
            int slot = i * 256 + tid;
            int row  = slot >> 3;
            int kq   = (slot & 7) << 2;
            float4 a = *(const float4*)(A + (size_t)row * lda + k0 + kq);
            *(uint2*)&As[row][kq] = pack4(a);
            float4 w = *(const float4*)(W + (size_t)(n0 + row) * ldw + koff + k0 + kq);
            *(uint2*)&Bs[row][kq] = pack4(w);
        }
        __syncthreads();
        bf16x8 af[2], bfr[2];
#pragma unroll
        for (int t = 0; t < 2; ++t) af[t]  = *(bf16x8*)&As[wm * 32 + t * 16 + l16][q * 8];
#pragma unroll
        for (int t = 0; t < 2; ++t) bfr[t] = *(bf16x8*)&Bs[wn * 32 + t * 16 + l16][q * 8];
#pragma unroll
        for (int tm = 0; tm < 2; ++tm)
#pragma unroll
            for (int tn = 0; tn < 2; ++tn)
                acc[tm][tn] = __builtin_amdgcn_mfma_f32_16x16x32_bf16(
                    af[tm], bfr[tn], acc[tm][tn], 0, 0, 0);
    }

#pragma unroll
    for (int tm = 0; tm < 2; ++tm) {
#pragma unroll
        for (int r = 0; r < 4; ++r) {
            int b = wm * 32 + tm * 16 + q * 4 + r;
#pragma unroll
            for (int tn = 0; tn < 2; ++tn) {
                int n = n0 + wn * 32 + tn * 16 + l16;
                float v = acc[tm][tn][r];
                if (addbias) v += bias[n];
                atomicAdd(&C[(size_t)b * N + n], v);
            }
        }
    }
}

// ---------------------------------------------------------------------------
// Prep kernel: grouped small GEMMs | fp32->bf16 convert | x-gather. grid 28352.
//  n < 640        : hbz (128 blk) | hbu (128) | gh (384)  (h0 @ W^T + bias)
//  640..28287     : convert u_enc | z_enc | azW[:,1024:] | auW[:,1024:] | c2W
//  28288..28351   : gather x[b] = [emb | . | . | degree]
// ---------------------------------------------------------------------------
__global__ __launch_bounds__(256) void k_prep(
    const float* __restrict__ u_enc, const float* __restrict__ z_enc,
    const float* __restrict__ azW, const float* __restrict__ auW,
    const float* __restrict__ c2W,
    unsigned short* __restrict__ ubf, unsigned short* __restrict__ zbf,
    unsigned short* __restrict__ azWbf, unsigned short* __restrict__ auWbf,
    unsigned short* __restrict__ c2Wbf,
    const int* __restrict__ mt, const float* __restrict__ embW,
    const float* __restrict__ degree, float* __restrict__ x,
    const float* __restrict__ h0,
    const float* __restrict__ azb, float* __restrict__ hbz,
    const float* __restrict__ aub, float* __restrict__ hbu,
    const float* __restrict__ Whh, const float* __restrict__ bhh,
    float* __restrict__ gh)
{
    __shared__ short As[64][40];
    __shared__ short Bs[64][40];
    int n = blockIdx.x, tid = threadIdx.x;
    if (n < 640) {
        const float *W, *bias; float* C; int ldw, N, n0, kc;
        if (n < 128)      { W = azW; bias = azb; C = hbz; ldw = 2048; N = 1024; n0 = (n & 15) * 64;  kc = n >> 4; }
        else if (n < 256) { int m = n - 128; W = auW; bias = aub; C = hbu; ldw = 2048; N = 1024; n0 = (m & 15) * 64; kc = m >> 4; }
        else              { int m = n - 256; W = Whh; bias = bhh; C = gh;  ldw = 1024; N = 3072; n0 = (m % 48) * 64; kc = m / 48; }
        gemm_core(As, Bs, tid, h0, 1024, W, ldw, 0, bias, C, N, n0, kc * 4, kc * 4 + 4, kc == 0);
        return;
    }
    n -= 640;
    if (n >= 27648) {   // gather path
        int b = n - 27648;
        int m = mt[b];
        for (int k = tid; k < E; k += 256) x[(size_t)b * GIN + k] = embW[(size_t)m * E + k];
        if (tid < DG) x[(size_t)b * GIN + E + 2 * H + tid] = degree[b * DG + tid];
        return;
    }
    int k4 = tid * 4;
    const float* src; unsigned short* dst; int ld, koff, r;
    if (n < 16384)      { src = u_enc; dst = ubf;   ld = 1024; koff = 0;    r = n; }
    else if (n < 24576) { src = z_enc; dst = zbf;   ld = 1024; koff = 0;    r = n - 16384; }
    else if (n < 25600) { src = azW;   dst = azWbf; ld = 2048; koff = 1024; r = n - 24576; }
    else if (n < 26624) { src = auW;   dst = auWbf; ld = 2048; koff = 1024; r = n - 25600; }
    else                { src = c2W;   dst = c2Wbf; ld = 1024; koff = 0;    r = n - 26624; }
    float4 v = *(const float4*)(src + (size_t)r * ld + koff + k4);
    *(uint2*)(dst + (size_t)r * 1024 + k4) = pack4(v);
}

// ---------------------------------------------------------------------------
// Merged big fused kernel, 8-wave + double-buffered prefetch version.
// grid 2048 linear, block 512 (8 waves, 2x4 wave grid, 128x128 tile).
//  gid < 1024 : z-side (M=8192, A=zbf). by = gid>>6:
//      by < 8 : scores_z epilogue (add=hbz, vec=azv)
//      by >= 8: tz = tanh(z @ c2W^T + c2b) materialized fp32
//  gid >= 1024: u-side (M=16384, A=ubf). scores_u epilogue (add=hbu, vec=auv)
// K-loop: STAGE(next buf) issued BEFORE compute(cur buf); single barrier/step
// (its implicit vmcnt(0)+lgkmcnt(0) drains the async stage and fences reuse).
// ---------------------------------------------------------------------------
__global__ __launch_bounds__(512, 4) void ftd_all(
    const unsigned short* __restrict__ zbf_, const unsigned short* __restrict__ ubf_,
    const unsigned short* __restrict__ azWbf, const unsigned short* __restrict__ auWbf,
    const unsigned short* __restrict__ c2Wbf,
    const float* __restrict__ hbz, const float* __restrict__ hbu,
    const float* __restrict__ azv, const float* __restrict__ auv,
    const float* __restrict__ c2b,
    float* __restrict__ scores_z, float* __restrict__ scores_u,
    float* __restrict__ tz)
{
    __shared__ unsigned short As[2][128 * 32];
    __shared__ unsigned short Bs[2][128 * 32];
    const int tid  = threadIdx.x;
    const int wave = tid >> 6, lane = tid & 63;
    const int wm = wave >> 2, wn = wave & 3;      // 2 x 4 wave grid
    const int q = lane >> 4, l16 = lane & 15;
    const int lrow = lane >> 2;                   // 16 rows per wave stage
    const int lk   = (lane & 3) * 8;
    const int r0   = wave * 16;

    const int gid = blockIdx.x;
    const bool isU = gid >= 1024;
    int m0, n0;
    const unsigned short *A, *W;
    bool isTZ = false;
    const float* addv; const float* vvec; float* outs;
    if (isU) {
        int g = gid - 1024;
        m0 = (g & 127) * 128;
        n0 = (g >> 7) * 128;
        A = ubf_; W = auWbf;
        addv = hbu; vvec = auv; outs = scores_u;
    } else {
        m0 = (gid & 63) * 128;
        int by = gid >> 6;
        A = zbf_;
        if (by < 8) { n0 = by * 128; W = azWbf; addv = hbz; vvec = azv; outs = scores_z; }
        else        { n0 = (by - 8) * 128; W = c2Wbf; isTZ = true; addv = nullptr; vvec = nullptr; outs = nullptr; }
    }

    f32x4 acc[4][2];
#pragma unroll
    for (int i = 0; i < 4; ++i)
#pragma unroll
        for (int j = 0; j < 2; ++j) acc[i][j] = f32x4{0.f, 0.f, 0.f, 0.f};

    const size_t arow = (size_t)(m0 + r0 + lrow) * 1024 + lk;
    const size_t brow = (size_t)(n0 + r0 + lrow) * 1024 + lk;

    // prologue: stage k-tile 0 into buf 0
    gl_lds16(A + arow, &As[0][r0 * 32]);
    gl_lds16(W + brow, &Bs[0][r0 * 32]);
    __syncthreads();

    int cur = 0;
    for (int kt = 0; kt < 32; ++kt) {
        if (kt < 31) {
            const int k1 = (kt + 1) * 32;
            gl_lds16(A + arow + k1, &As[cur ^ 1][r0 * 32]);
            gl_lds16(W + brow + k1, &Bs[cur ^ 1][r0 * 32]);
        }
        bf16x8 af[4], bfr[2];
#pragma unroll
        for (int t = 0; t < 4; ++t) af[t]  = *(bf16x8*)&As[cur][(wm * 64 + t * 16 + l16) * 32 + q * 8];
#pragma unroll
        for (int t = 0; t < 2; ++t) bfr[t] = *(bf16x8*)&Bs[cur][(wn * 32 + t * 16 + l16) * 32 + q * 8];
#pragma unroll
        for (int tm = 0; tm < 4; ++tm)
#pragma unroll
            for (int tn = 0; tn < 2; ++tn)
                acc[tm][tn] = __builtin_amdgcn_mfma_f32_16x16x32_bf16(
                    af[tm], bfr[tn], acc[tm][tn], 0, 0, 0);
        __syncthreads();
        cur ^= 1;
    }

    if (!isTZ) {
#pragma unroll
        for (int tm = 0; tm < 4; ++tm) {
#pragma unroll
            for (int r = 0; r < 4; ++r) {
                int R = m0 + wm * 64 + tm * 16 + q * 4 + r;
                int b = R & 63;
                float s = 0.f;
#pragma unroll
                for (int tn = 0; tn < 2; ++tn) {
                    int col = n0 + wn * 32 + tn * 16 + l16;
                    float e = acc[tm][tn][r] + addv[(size_t)b * 1024 + col];
                    s += fast_tanh(e) * vvec[col];
                }
                s += __shfl_xor(s, 1);
                s += __shfl_xor(s, 2);
                s += __shfl_xor(s, 4);
                s += __shfl_xor(s, 8);
                if (l16 == 0) atomicAdd(&outs[R], s);
            }
        }
    } else {
#pragma unroll
        for (int tm = 0; tm < 4; ++tm) {
#pragma unroll
            for (int r = 0; r < 4; ++r) {
                int R = m0 + wm * 64 + tm * 16 + q * 4 + r;
#pragma unroll
                for (int tn = 0; tn < 2; ++tn) {
                    int col = n0 + wn * 32 + tn * 16 + l16;
                    tz[(size_t)R * 1024 + col] = fast_tanh(acc[tm][tn][r] + c2b[col]);
                }
            }
        }
    }
}

// generic single-GEMM launch (used for gi)
__global__ __launch_bounds__(256) void gemm_bt_mfma(
    const float* __restrict__ A, int lda,
    const float* __restrict__ W, int ldw, int koff,
    const float* __restrict__ bias,
    float* __restrict__ C, int N,
    int ks_total, int ks_chunk)
{
    __shared__ short As[64][40];
    __shared__ short Bs[64][40];
    int n0 = blockIdx.x * 64;
    int kb = blockIdx.y * ks_chunk;
    int ke = min(kb + ks_chunk, ks_total);
    gemm_core(As, Bs, threadIdx.x, A, lda, W, ldw, koff, bias, C, N,
              n0, kb, ke, blockIdx.y == 0);
}

// softmax over t + ctx, both sides in one launch. grid (64,4), block 256.
//  y<2: z side (T=128), y>=2: u side (T=256); hc = y&1 selects h-half.
__global__ __launch_bounds__(256) void k_softmax_ctx_bf(
    const float* __restrict__ scores_z, const float* __restrict__ scores_u,
    const unsigned short* __restrict__ zbf_, const unsigned short* __restrict__ ubf_,
    float* __restrict__ x, float* __restrict__ y)
{
    __shared__ float red[256];
    __shared__ float al[256];
    int b = blockIdx.x, tid = threadIdx.x;
    int side = blockIdx.y >> 1, hc = blockIdx.y & 1;
    const float* scores = side ? scores_u : scores_z;
    const unsigned short* encbf = side ? ubf_ : zbf_;
    int T = side ? TU : TZ;
    int xoff = side ? 512 : 1536;
    int yoff = side ? 1024 : 0;

    float s = (tid < T) ? scores[tid * B64 + b] : -1e30f;
    red[tid] = s; __syncthreads();
    for (int off = 128; off > 0; off >>= 1) {
        if (tid < off) red[tid] = fmaxf(red[tid], red[tid + off]);
        __syncthreads();
    }
    float mx = red[0]; __syncthreads();
    float e = (tid < T) ? __expf(s - mx) : 0.f;
    red[tid] = e; __syncthreads();
    for (int off = 128; off > 0; off >>= 1) {
        if (tid < off) red[tid] += red[tid + off];
        __syncthreads();
    }
    float inv = 1.f / red[0];
    al[tid] = e * inv;
    __syncthreads();
    int h = hc * 512 + tid * 2;
    float a0 = 0.f, a1 = 0.f;
#pragma unroll 4
    for (int t = 0; t < T; ++t) {
        unsigned u = *(const unsigned*)(encbf + ((size_t)t * B64 + b) * 1024 + h);
        float w = al[t];
        a0 += w * __uint_as_float(u << 16);
        a1 += w * __uint_as_float(u & 0xffff0000u);
    }
    x[(size_t)b * GIN + xoff + h]     = a0;
    x[(size_t)b * GIN + xoff + h + 1] = a1;
    y[(size_t)b * 3072 + yoff + h]     = a0;
    y[(size_t)b * 3072 + yoff + h + 1] = a1;
}

// ---------------------------------------------------------------------------
// GRU gate (recomputed per block, LDS-resident) + z_cs dot.
// grid (64,4), block 512. quarter-0 blocks write gru outputs.
// zraw[b*TZ + t] = dot(tanh-energy tz[t*64+b,:], gate(b,:)).
// ---------------------------------------------------------------------------
__global__ __launch_bounds__(512) void k_zcs_gate(
    const float* __restrict__ gi, const float* __restrict__ gh,
    const float* __restrict__ h0, const float* __restrict__ tz,
    float* __restrict__ zraw,
    float* __restrict__ y, float* __restrict__ out_hid,
    float* __restrict__ out_gru)
{
    __shared__ float g[1024];
    int b = blockIdx.x, quarter = blockIdx.y, tid = threadIdx.x;
    int wave = tid >> 6, lane = tid & 63;
    for (int j = tid; j < H; j += 512) {
        float ir = gi[(size_t)b * 3072 + j];
        float iz = gi[(size_t)b * 3072 + H + j];
        float in_ = gi[(size_t)b * 3072 + 2 * H + j];
        float hr = gh[(size_t)b * 3072 + j];
        float hz = gh[(size_t)b * 3072 + H + j];
        float hn = gh[(size_t)b * 3072 + 2 * H + j];
        float r = fast_sig(ir + hr);
        float z = fast_sig(iz + hz);
        float nn = fast_tanh(in_ + r * hn);
        float h = h0[(size_t)b * H + j];
        float o = (1.f - z) * nn + z * h;
        g[j] = o;
        if (quarter == 0) {
            y[(size_t)b * 3072 + 2 * H + j] = o;
            out_hid[(size_t)b * H + j] = o;
            out_gru[(size_t)b * H + j] = o;
        }
    }
    __syncthreads();
    float gr[16];
#pragma unroll
    for (int j = 0; j < 16; ++j) gr[j] = g[lane * 16 + j];
    int t0 = quarter * 32;
#pragma unroll
    for (int i = 0; i < 4; ++i) {
        int t = t0 + wave + i * 8;
        const float* row = tz + ((size_t)t * B64 + b) * 1024 + lane * 16;
        float s = 0.f;
#pragma unroll
        for (int c = 0; c < 4; ++c) {
            float4 v = *(const float4*)(row + c * 4);
            s += v.x * gr[c * 4 + 0] + v.y * gr[c * 4 + 1]
               + v.z * gr[c * 4 + 2] + v.w * gr[c * 4 + 3];
        }
#pragma unroll
        for (int off = 32; off > 0; off >>= 1) s += __shfl_xor(s, off);
        if (lane == 0) zraw[b * TZ + t] = s;
    }
}

// ---------------------------------------------------------------------------
// Merged gen GEMM + sparse log-sum-exp. grid 1512, block 256.
//  n < 512  : sparse (c = n&7, b = n>>3)  -- BW-bound, dispatched first
//  n >= 512 : gen = y @ pW^T + pb (n0 = (g%125)*64, K-chunk g/125 of 8)
// ---------------------------------------------------------------------------
__global__ __launch_bounds__(256) void k_gen_sparse(
    const float* __restrict__ y, const float* __restrict__ pW,
    const float* __restrict__ pb, float* __restrict__ gen,
    const float* __restrict__ sz, const float* __restrict__ zraw,
    float* __restrict__ zcopy)
{
    __shared__ short As[64][40];
    __shared__ short Bs[64][40];
    __shared__ float es[TZ];
    __shared__ float mred[2];
    int n = blockIdx.x, tid = threadIdx.x;
    if (n >= 512) {
        int gblk = n - 512;
        int n0 = (gblk % 125) * 64;
        int kc = gblk / 125;
        gemm_core(As, Bs, tid, y, 3072, pW, 3072, 0, pb, gen, 8000,
                  n0, kc * 12, kc * 12 + 12, kc == 0);
        return;
    }
    int c = n & 7, b = n >> 3;
    float sv = 0.f;
    if (tid < TZ) {
        sv = zraw[b * TZ + tid];
        float mm = sv;
#pragma unroll
        for (int off = 32; off > 0; off >>= 1) mm = fmaxf(mm, __shfl_xor(mm, off));
        if ((tid & 63) == 0) mred[tid >> 6] = mm;
    }
    __syncthreads();
    float m = fmaxf(mred[0], mred[1]);
    if (tid < TZ) es[tid] = __expf(sv - m);
    __syncthreads();
    if (tid >= 254) return;
    int v4 = c * 254 + tid;               // 8 * 254 = 2032 = 8128/4, exact cover
    const f32x4* base = (const f32x4*)(sz + (size_t)b * TZ * VT);
    float4 acc = make_float4(0.f, 0.f, 0.f, 0.f);
#pragma unroll 16
    for (int t = 0; t < TZ; ++t) {
        f32x4 xv = __builtin_nontemporal_load(&base[(size_t)t * (VT / 4) + v4]);
        float e = es[t];
        acc.x += e * xv[0]; acc.y += e * xv[1]; acc.z += e * xv[2]; acc.w += e * xv[3];
    }
    int v = v4 * 4;
    zcopy[(size_t)b * VT + v + 0] = __logf(acc.x) + m;
    zcopy[(size_t)b * VT + v + 1] = __logf(acc.y) + m;
    zcopy[(size_t)b * VT + v + 2] = __logf(acc.z) + m;
    zcopy[(size_t)b * VT + v + 3] = __logf(acc.w) + m;
}

// final softmax over [gen(8000) | zcopy(8128)]; proba combine. grid 64, block 1024.
__global__ __launch_bounds__(1024) void k_final(
    const float* __restrict__ gen, const float* __restrict__ zcopy,
    float* __restrict__ proba)
{
    __shared__ float lg[NC];
    __shared__ float wred[16];
    int b = blockIdx.x, tid = threadIdx.x;
    int lane = tid & 63, wave = tid >> 6;
    for (int i = tid; i < V; i += 1024) lg[i] = gen[(size_t)b * V + i];
    for (int i = tid; i < VT; i += 1024) lg[V + i] = zcopy[(size_t)b * VT + i];
    __syncthreads();
    float mx = -1e30f;
    for (int i = tid; i < NC; i += 1024) mx = fmaxf(mx, lg[i]);
#pragma unroll
    for (int off = 32; off > 0; off >>= 1) mx = fmaxf(mx, __shfl_xor(mx, off));
    if (lane == 0) wred[wave] = mx;
    __syncthreads();
    mx = wred[0];
#pragma unroll
    for (int w = 1; w < 16; ++w) mx = fmaxf(mx, wred[w]);
    __syncthreads();
    float sm = 0.f;
    for (int i = tid; i < NC; i += 1024) sm += __expf(lg[i] - mx);
#pragma unroll
    for (int off = 32; off > 0; off >>= 1) sm += __shfl_xor(sm, off);
    if (lane == 0) wred[wave] = sm;
    __syncthreads();
    float Z = 0.f;
#pragma unroll
    for (int w = 0; w < 16; ++w) Z += wred[w];
    float invZ = 1.f / Z;
    for (int v = tid; v < VT; v += 1024) {
        float p = __expf(lg[V + v] - mx) * invZ;
        if (v < V) p += __expf(lg[v] - mx) * invZ;
        proba[(size_t)b * VT + v] = p;
    }
}

extern "C" void kernel_launch(void* const* d_in, const int* in_sizes, int n_in,
                              void* d_out, int out_size, void* d_ws, size_t ws_size,
                              hipStream_t stream)
{
    const float* z_enc  = (const float*)d_in[0];
    const float* u_enc  = (const float*)d_in[1];
    const int*   mt     = (const int*)d_in[2];
    const float* degree = (const float*)d_in[3];
    const float* h0     = (const float*)d_in[4];
    const float* sz     = (const float*)d_in[5];
    const float* embW   = (const float*)d_in[6];
    const float* azW    = (const float*)d_in[7];
    const float* azb    = (const float*)d_in[8];
    const float* azv    = (const float*)d_in[9];
    const float* auW    = (const float*)d_in[10];
    const float* aub    = (const float*)d_in[11];
    const float* auv    = (const float*)d_in[12];
    const float* Wih    = (const float*)d_in[13];
    const float* Whh    = (const float*)d_in[14];
    const float* bih    = (const float*)d_in[15];
    const float* bhh    = (const float*)d_in[16];
    const float* pW     = (const float*)d_in[17];
    const float* pb     = (const float*)d_in[18];
    const float* c2W    = (const float*)d_in[19];
    const float* c2b    = (const float*)d_in[20];

    float* ws       = (float*)d_ws;
    // zeroed region (atomic accumulators), contiguous:
    float* scores_z = ws;               // 8192   (t*64+b)
    float* scores_u = ws + 8192;        // 16384
    float* hbz      = ws + 32768;       // 65536
    float* hbu      = ws + 98304;       // 65536
    float* gi       = ws + 163840;      // 196608 (64*3072)
    float* gh       = ws + 360448;      // 196608
    float* gen      = ws + 557056;      // 512000 (64*8000)
    // non-zeroed:
    float* x        = ws + 1069056;     // 64*2624
    float* y        = ws + 1236992;     // 64*3072
    float* zcopy    = ws + 1507392;     // 64*8128
    float* tz       = ws + 2027584;     // 8192*1024 fp32 tanh-energy
    // bf16 area (shorts)
    unsigned short* ubf   = (unsigned short*)(ws + 2027584 + 8388608);
    unsigned short* zbf   = ubf + (size_t)16384 * 1024;
    unsigned short* azWbf = zbf + (size_t)8192 * 1024;
    unsigned short* auWbf = azWbf + (size_t)1024 * 1024;
    unsigned short* c2Wbf = auWbf + (size_t)1024 * 1024;
    // scratch after bf16 area (float offset 24,571,968)
    float* zraw = ws + 24571968;        // 64*128

    float* out_proba = (float*)d_out;
    float* out_hid   = out_proba + (size_t)B64 * VT;
    float* out_gru   = out_hid + (size_t)B64 * H;

    // zero all atomic accumulators in one shot
    hipMemsetAsync(ws, 0, 1069056 * sizeof(float), stream);

    // prep: small GEMMs (hbz|hbu|gh) + fp32->bf16 convert + x gather, one launch
    k_prep<<<28352, 256, 0, stream>>>(u_enc, z_enc, azW, auW, c2W,
                                      ubf, zbf, azWbf, auWbf, c2Wbf,
                                      mt, embW, degree, x,
                                      h0, azb, hbz, aub, hbu, Whh, bhh, gh);

    // merged big fused kernel: scores_z + tz + scores_u (8-wave dbuf version)
    ftd_all<<<2048, 512, 0, stream>>>(zbf, ubf, azWbf, auWbf, c2Wbf,
                                      hbz, hbu, azv, auv, c2b,
                                      scores_z, scores_u, tz);

    // softmax over t + ctx, both sides
    k_softmax_ctx_bf<<<dim3(64, 4), 256, 0, stream>>>(scores_z, scores_u, zbf, ubf, x, y);

    // GRU: gi = x @ Wih^T + bih  (K=2624 -> 82 k-steps, 8 chunks of 11)
    gemm_bt_mfma<<<dim3(48, 8), 256, 0, stream>>>(x, GIN, Wih, GIN, 0, bih, gi, 3072, 82, 11);

    // GRU gate (LDS-recompute) + z_cs dot
    k_zcs_gate<<<dim3(64, 4), 512, 0, stream>>>(gi, gh, h0, tz, zraw, y, out_hid, out_gru);

    // gen GEMM + sparse log-sum-exp, one launch (sparse blocks first)
    k_gen_sparse<<<1512, 256, 0, stream>>>(y, pW, pb, gen, sz, zraw, zcopy);

    // final softmax + combine
    k_final<<<64, 1024, 0, stream>>>(gen, zcopy, out_proba);
}